// Round 1
// baseline (51.725 us; speedup 1.0000x reference)
//
#include <hip/hip_runtime.h>
#include <math.h>

#define RES 128
#define TOPK 16
#define NPTS 192
#define NQ 64                    // 4 tasks * 16 points
#define SIGMA_F (6.0f / 128.0f)
#define INV2S2 (1.0f / (2.0f * SIGMA_F * SIGMA_F))
#define NBLK 512                 // main kernel blocks
#define TAB_OFF 1024             // float offset of tables in ws
#define NPAIRS (RES * RES)

// ---------------------------------------------------------------------------
// Kernel A: top-16 per (set,batch), renormalize, bounds, Gaussian axis tables.
// 1 block, 256 threads (4 waves; wave = task).
// task: 0 = set1/b0, 1 = set1/b1, 2 = set2/b0, 3 = set2/b1
// Tables (in ws, float offsets):
//   tabXw[q][128] at TAB_OFF           (w folded in)
//   tabY [q][128] at TAB_OFF +  8192
//   tabZ [q][128] at TAB_OFF + 16384
// ---------------------------------------------------------------------------
__global__ __launch_bounds__(256) void iou_prep_kernel(
    const float* __restrict__ pts1, const float* __restrict__ w1,
    const float* __restrict__ pts2, const float* __restrict__ w2,
    float* __restrict__ ws)
{
    __shared__ float sp[NQ][3];
    __shared__ float sw[NQ];
    __shared__ float slo[3], shi[3];

    const int tid  = threadIdx.x;
    const int lane = tid & 63;
    const int wave = tid >> 6;          // task id
    const int set  = wave >> 1;
    const int b    = wave & 1;

    const float* w   = (set ? w2 : w1) + b * NPTS;
    const float* pts = (set ? pts2 : pts1) + b * NPTS * 3;

    // each lane holds 3 of the 192 weights
    float v0 = w[lane];
    float v1 = w[lane + 64];
    float v2 = w[lane + 128];

    float myv = 0.0f;
    int   myi = 0;
    float wsum = 0.0f;

    for (int it = 0; it < TOPK; ++it) {
        // local argmax (lowest index wins ties -> only strict > replaces)
        float bv = v0; int bi = lane;
        if (v1 > bv) { bv = v1; bi = lane + 64; }
        if (v2 > bv) { bv = v2; bi = lane + 128; }
        // wave argmax, butterfly
        #pragma unroll
        for (int m = 32; m; m >>= 1) {
            float ov = __shfl_xor(bv, m, 64);
            int   oi = __shfl_xor(bi, m, 64);
            if (ov > bv || (ov == bv && oi < bi)) { bv = ov; bi = oi; }
        }
        wsum += bv;                      // same on all lanes
        if (lane == it) { myv = bv; myi = bi; }
        // knock out the winner (weights are uniform[0,1), so -1 is safe)
        if      (bi == lane)       v0 = -1.0f;
        else if (bi == lane + 64)  v1 = -1.0f;
        else if (bi == lane + 128) v2 = -1.0f;
    }

    if (lane < TOPK) {
        int q = wave * TOPK + lane;
        sw[q]    = myv / (wsum + 1e-5f);
        sp[q][0] = pts[myi * 3 + 0];
        sp[q][1] = pts[myi * 3 + 1];
        sp[q][2] = pts[myi * 3 + 2];
    }
    __syncthreads();

    // per-axis bounds over all 64 selected points, padded by 3*sigma
    if (tid < 6) {
        const int  axis  = tid % 3;
        const bool ismax = tid >= 3;
        float r = sp[0][axis];
        for (int q = 1; q < NQ; ++q) {
            float v = sp[q][axis];
            r = ismax ? fmaxf(r, v) : fminf(r, v);
        }
        if (ismax) shi[axis] = r + 3.0f * SIGMA_F;
        else       slo[axis] = r - 3.0f * SIGMA_F;
    }
    __syncthreads();

    // axis tables: 3 * 64 * 128 = 24576 entries
    for (int e = tid; e < 3 * NQ * RES; e += 256) {
        const int axis = e >> 13;        // / 8192
        const int rem  = e & 8191;
        const int q    = rem >> 7;       // point index
        const int i    = rem & 127;      // grid index
        const float lo = slo[axis];
        const float hi = shi[axis];
        const float c  = lo + (float)i * (hi - lo) * (1.0f / 127.0f);
        const float d  = c - sp[q][axis];
        float g = expf(-d * d * INV2S2);
        if (axis == 0) g *= sw[q];       // fold weight into X table
        ws[TAB_OFF + e] = g;
    }
}

// ---------------------------------------------------------------------------
// Kernel B: main accumulation. Wave owns lane=iz (two 64-halves in regs),
// loops over (ix,iy) pairs. Per-block partial I/U -> ws[0..NBLK-1], ws[NBLK..].
// ---------------------------------------------------------------------------
__global__ __launch_bounds__(256) void iou_heat_kernel(
    const float* __restrict__ ws, float* __restrict__ partials)
{
    const float* __restrict__ tabX = ws + TAB_OFF;
    const float* __restrict__ tabY = tabX + NQ * RES;
    const float* __restrict__ tabZ = tabY + NQ * RES;

    const int lane = threadIdx.x & 63;
    const int wid  = threadIdx.x >> 6;
    const int gw   = blockIdx.x * 4 + wid;   // global wave id
    const int NW   = NBLK * 4;

    // Gz fragments: lane = iz (low half) and iz+64 (high half)
    float zlo[NQ], zhi[NQ];
    #pragma unroll
    for (int q = 0; q < NQ; ++q) {
        zlo[q] = tabZ[q * RES + lane];
        zhi[q] = tabZ[q * RES + 64 + lane];
    }

    float Iacc = 0.0f, Uacc = 0.0f;

    for (int pair = gw; pair < NPAIRS; pair += NW) {
        const int up = __builtin_amdgcn_readfirstlane(pair);
        const int ix = up >> 7;
        const int iy = up & 127;

        float h0lo = 0, h1lo = 0, h2lo = 0, h3lo = 0;
        float h0hi = 0, h1hi = 0, h2hi = 0, h3hi = 0;
        #pragma unroll
        for (int k = 0; k < TOPK; ++k) {
            {
                const int q = k;
                const float a = tabX[q * RES + ix] * tabY[q * RES + iy];
                h0lo += a * zlo[q]; h0hi += a * zhi[q];
            }
            {
                const int q = 16 + k;
                const float a = tabX[q * RES + ix] * tabY[q * RES + iy];
                h1lo += a * zlo[q]; h1hi += a * zhi[q];
            }
            {
                const int q = 32 + k;
                const float a = tabX[q * RES + ix] * tabY[q * RES + iy];
                h2lo += a * zlo[q]; h2hi += a * zhi[q];
            }
            {
                const int q = 48 + k;
                const float a = tabX[q * RES + ix] * tabY[q * RES + iy];
                h3lo += a * zlo[q]; h3hi += a * zhi[q];
            }
        }
        // h0/h1 = heatmap1 (b=0/1), h2/h3 = heatmap2 (b=0/1)
        float p;
        p = h0lo * h2lo; Iacc += p; Uacc += h0lo + h2lo - p;
        p = h1lo * h3lo; Iacc += p; Uacc += h1lo + h3lo - p;
        p = h0hi * h2hi; Iacc += p; Uacc += h0hi + h2hi - p;
        p = h1hi * h3hi; Iacc += p; Uacc += h1hi + h3hi - p;
    }

    // wave reduce
    #pragma unroll
    for (int m = 32; m; m >>= 1) {
        Iacc += __shfl_xor(Iacc, m, 64);
        Uacc += __shfl_xor(Uacc, m, 64);
    }
    __shared__ float rI[4], rU[4];
    if (lane == 0) { rI[wid] = Iacc; rU[wid] = Uacc; }
    __syncthreads();
    if (threadIdx.x == 0) {
        partials[blockIdx.x]        = rI[0] + rI[1] + rI[2] + rI[3];
        partials[NBLK + blockIdx.x] = rU[0] + rU[1] + rU[2] + rU[3];
    }
}

// ---------------------------------------------------------------------------
// Kernel C: deterministic final reduce of NBLK partials; scalar output.
// ---------------------------------------------------------------------------
__global__ __launch_bounds__(256) void iou_final_kernel(
    const float* __restrict__ ws, float* __restrict__ out)
{
    __shared__ float rI[4], rU[4];
    const int tid  = threadIdx.x;
    const int lane = tid & 63;
    const int wid  = tid >> 6;

    float I = 0.0f, U = 0.0f;
    for (int i = tid; i < NBLK; i += 256) {
        I += ws[i];
        U += ws[NBLK + i];
    }
    #pragma unroll
    for (int m = 32; m; m >>= 1) {
        I += __shfl_xor(I, m, 64);
        U += __shfl_xor(U, m, 64);
    }
    if (lane == 0) { rI[wid] = I; rU[wid] = U; }
    __syncthreads();
    if (tid == 0) {
        const float It = rI[0] + rI[1] + rI[2] + rI[3];
        const float Ut = rU[0] + rU[1] + rU[2] + rU[3] + 1e-5f;
        out[0] = 1.0f - It / Ut;
    }
}

extern "C" void kernel_launch(void* const* d_in, const int* in_sizes, int n_in,
                              void* d_out, int out_size, void* d_ws, size_t ws_size,
                              hipStream_t stream)
{
    const float* pts1 = (const float*)d_in[0];   // [2,192,3]
    const float* w1   = (const float*)d_in[1];   // [2,192]
    const float* pts2 = (const float*)d_in[2];   // [2,192,3]
    const float* w2   = (const float*)d_in[3];   // [2,192]
    float* out = (float*)d_out;                  // scalar
    float* ws  = (float*)d_ws;                   // >= (1024 + 24576) floats

    iou_prep_kernel<<<1, 256, 0, stream>>>(pts1, w1, pts2, w2, ws);
    iou_heat_kernel<<<NBLK, 256, 0, stream>>>(ws, ws);  // partials at ws[0..2*NBLK)
    iou_final_kernel<<<1, 256, 0, stream>>>(ws, out);
}

// Round 2
// 47.994 us; speedup vs baseline: 1.0777x; 1.0777x over previous
//
#include <hip/hip_runtime.h>
#include <math.h>

#define RES 128
#define TOPK 16
#define NPTS 192
#define NQ 64                    // 4 tasks * 16 points
#define SIGMA_F (6.0f / 128.0f)
#define INV2S2 (1.0f / (2.0f * SIGMA_F * SIGMA_F))
#define NBLK 512
#define NWAVES (NBLK * 4)
#define NPAIRS (RES * RES)

// ---------------------------------------------------------------------------
// Fused kernel: every block redundantly does prep (top-16 per task, renorm,
// bounds, X/Y Gaussian tables -> LDS transposed [i][q], Z fragments -> regs),
// then all waves sweep (ix,iy) pairs accumulating I and U. One partial pair
// per block -> ws.
// task: 0 = set1/b0, 1 = set1/b1, 2 = set2/b0, 3 = set2/b1
// ---------------------------------------------------------------------------
__global__ __launch_bounds__(256, 2) void iou_fused_kernel(
    const float* __restrict__ pts1, const float* __restrict__ w1,
    const float* __restrict__ pts2, const float* __restrict__ w2,
    float* __restrict__ partials)
{
    __shared__ float tX[RES * NQ];   // [i][q], weight folded in
    __shared__ float tY[RES * NQ];   // [i][q]
    __shared__ float sp[NQ][3];
    __shared__ float sw[NQ];
    __shared__ float sbound[6];      // lo x,y,z ; hi x,y,z

    const int tid  = threadIdx.x;
    const int lane = tid & 63;
    const int wave = tid >> 6;       // task id for prep

    // ---- phase 1: top-16 per (set,batch); wave == task ----
    {
        const int set = wave >> 1;
        const int b   = wave & 1;
        const float* w   = (set ? w2 : w1) + b * NPTS;
        const float* pts = (set ? pts2 : pts1) + b * NPTS * 3;

        float v0 = w[lane];
        float v1 = w[lane + 64];
        float v2 = w[lane + 128];

        float myv = 0.0f;
        int   myi = 0;
        float wsum = 0.0f;

        for (int it = 0; it < TOPK; ++it) {
            // local argmax, lowest index wins ties (strict > only)
            float bv = v0; int bi = lane;
            if (v1 > bv) { bv = v1; bi = lane + 64; }
            if (v2 > bv) { bv = v2; bi = lane + 128; }
            #pragma unroll
            for (int m = 32; m; m >>= 1) {
                float ov = __shfl_xor(bv, m, 64);
                int   oi = __shfl_xor(bi, m, 64);
                if (ov > bv || (ov == bv && oi < bi)) { bv = ov; bi = oi; }
            }
            wsum += bv;
            if (lane == it) { myv = bv; myi = bi; }
            if      (bi == lane)       v0 = -1.0f;   // weights are U[0,1)
            else if (bi == lane + 64)  v1 = -1.0f;
            else if (bi == lane + 128) v2 = -1.0f;
        }
        if (lane < TOPK) {
            int q = wave * TOPK + lane;
            sw[q]    = myv / (wsum + 1e-5f);
            sp[q][0] = pts[myi * 3 + 0];
            sp[q][1] = pts[myi * 3 + 1];
            sp[q][2] = pts[myi * 3 + 2];
        }
    }
    __syncthreads();

    // ---- phase 2: per-axis bounds over all 64 selected points ----
    if (tid < 6) {
        const int  axis  = tid % 3;
        const bool ismax = tid >= 3;
        float r = sp[0][axis];
        for (int q = 1; q < NQ; ++q) {
            float v = sp[q][axis];
            r = ismax ? fmaxf(r, v) : fminf(r, v);
        }
        sbound[tid] = ismax ? (r + 3.0f * SIGMA_F) : (r - 3.0f * SIGMA_F);
    }
    __syncthreads();

    const float lox = sbound[0], loy = sbound[1], loz = sbound[2];
    const float hix = sbound[3], hiy = sbound[4], hiz = sbound[5];

    // ---- phase 3a: X/Y tables into LDS, transposed [i][q] ----
    for (int e = tid; e < 2 * NQ * RES; e += 256) {
        const int isY = e >> 13;         // 0 = X table, 1 = Y table
        const int rem = e & 8191;
        const int i   = rem >> 6;        // grid index
        const int q   = rem & 63;        // point index
        const float lo = isY ? loy : lox;
        const float hi = isY ? hiy : hix;
        const float c  = lo + (float)i * (hi - lo) * (1.0f / 127.0f);
        const float d  = c - sp[q][isY];
        float g = __expf(-d * d * INV2S2);
        if (!isY) g *= sw[q];            // fold weight into X table
        (isY ? tY : tX)[rem] = g;
    }

    // ---- phase 3b: Z fragments in registers: lane = iz and iz+64 ----
    float zlo[NQ], zhi[NQ];
    {
        const float zstep = (hiz - loz) * (1.0f / 127.0f);
        const float clo = loz + (float)lane * zstep;
        const float chi = loz + (float)(lane + 64) * zstep;
        #pragma unroll
        for (int q = 0; q < NQ; ++q) {
            const float pz = sp[q][2];
            const float d0 = clo - pz;
            const float d1 = chi - pz;
            zlo[q] = __expf(-d0 * d0 * INV2S2);
            zhi[q] = __expf(-d1 * d1 * INV2S2);
        }
    }
    __syncthreads();

    // ---- phase 4: sweep (ix,iy) pairs ----
    float Iacc = 0.0f, Uacc = 0.0f;
    const int gw = blockIdx.x * 4 + wave;

    for (int pair = gw; pair < NPAIRS; pair += NWAVES) {
        const int ix = pair >> 7;
        const int iy = pair & 127;
        const float4* __restrict__ px = (const float4*)&tX[ix * NQ];
        const float4* __restrict__ py = (const float4*)&tY[iy * NQ];

        float hlo[4], hhi[4];
        #pragma unroll
        for (int t = 0; t < 4; ++t) {
            float alo = 0.0f, ahi = 0.0f;
            #pragma unroll
            for (int g4 = t * 4; g4 < t * 4 + 4; ++g4) {
                const float4 xv = px[g4];
                const float4 yv = py[g4];
                const int q = g4 * 4;
                const float a0 = xv.x * yv.x;
                const float a1 = xv.y * yv.y;
                const float a2 = xv.z * yv.z;
                const float a3 = xv.w * yv.w;
                alo += a0 * zlo[q]     + a1 * zlo[q + 1]
                     + a2 * zlo[q + 2] + a3 * zlo[q + 3];
                ahi += a0 * zhi[q]     + a1 * zhi[q + 1]
                     + a2 * zhi[q + 2] + a3 * zhi[q + 3];
            }
            hlo[t] = alo; hhi[t] = ahi;
        }
        // t0/t1 = heatmap1 (b=0/1), t2/t3 = heatmap2 (b=0/1)
        float p;
        p = hlo[0] * hlo[2]; Iacc += p; Uacc += hlo[0] + hlo[2] - p;
        p = hlo[1] * hlo[3]; Iacc += p; Uacc += hlo[1] + hlo[3] - p;
        p = hhi[0] * hhi[2]; Iacc += p; Uacc += hhi[0] + hhi[2] - p;
        p = hhi[1] * hhi[3]; Iacc += p; Uacc += hhi[1] + hhi[3] - p;
    }

    // ---- phase 5: block reduce, one I/U partial per block ----
    #pragma unroll
    for (int m = 32; m; m >>= 1) {
        Iacc += __shfl_xor(Iacc, m, 64);
        Uacc += __shfl_xor(Uacc, m, 64);
    }
    __shared__ float rI[4], rU[4];
    if (lane == 0) { rI[wave] = Iacc; rU[wave] = Uacc; }
    __syncthreads();
    if (tid == 0) {
        partials[blockIdx.x]        = rI[0] + rI[1] + rI[2] + rI[3];
        partials[NBLK + blockIdx.x] = rU[0] + rU[1] + rU[2] + rU[3];
    }
}

// ---------------------------------------------------------------------------
// Final deterministic reduce of NBLK partial pairs -> scalar loss.
// ---------------------------------------------------------------------------
__global__ __launch_bounds__(256) void iou_final_kernel(
    const float* __restrict__ ws, float* __restrict__ out)
{
    __shared__ float rI[4], rU[4];
    const int tid  = threadIdx.x;
    const int lane = tid & 63;
    const int wid  = tid >> 6;

    float I = 0.0f, U = 0.0f;
    for (int i = tid; i < NBLK; i += 256) {
        I += ws[i];
        U += ws[NBLK + i];
    }
    #pragma unroll
    for (int m = 32; m; m >>= 1) {
        I += __shfl_xor(I, m, 64);
        U += __shfl_xor(U, m, 64);
    }
    if (lane == 0) { rI[wid] = I; rU[wid] = U; }
    __syncthreads();
    if (tid == 0) {
        const float It = rI[0] + rI[1] + rI[2] + rI[3];
        const float Ut = rU[0] + rU[1] + rU[2] + rU[3] + 1e-5f;
        out[0] = 1.0f - It / Ut;
    }
}

extern "C" void kernel_launch(void* const* d_in, const int* in_sizes, int n_in,
                              void* d_out, int out_size, void* d_ws, size_t ws_size,
                              hipStream_t stream)
{
    const float* pts1 = (const float*)d_in[0];   // [2,192,3]
    const float* w1   = (const float*)d_in[1];   // [2,192]
    const float* pts2 = (const float*)d_in[2];   // [2,192,3]
    const float* w2   = (const float*)d_in[3];   // [2,192]
    float* out = (float*)d_out;                  // scalar
    float* ws  = (float*)d_ws;                   // >= 2*NBLK floats

    iou_fused_kernel<<<NBLK, 256, 0, stream>>>(pts1, w1, pts2, w2, ws);
    iou_final_kernel<<<1, 256, 0, stream>>>(ws, out);
}